// Round 1
// baseline (660.418 us; speedup 1.0000x reference)
//
#include <hip/hip_runtime.h>

// PWC-Net FunctionCorrelation (max_disp=4 -> 81 channels) + LeakyReLU(0.1)
// feat1, feat2: [8, 256, 80, 160] fp32 (NCHW). out: [8, 81, 80, 160] fp32.
// out[n, dy*9+dx, y, x] = leaky( (1/256) * sum_c f1[n,c,y,x] * f2pad[n,c,y+dy,x+dx] )
// where f2pad has a 4-pixel zero border.

constexpr int MAXD = 4;
constexpr int N_ = 8, C_ = 256, H_ = 80, W_ = 160;
constexpr int TH = 8, TW = 32;          // spatial tile per block
constexpr int CK = 8;                   // channels staged per LDS chunk
constexpr int S1_STRIDE = 36;           // 32 + 4 pad (keeps 16B align, bank-balanced)
constexpr int F2W = TW + 8;             // 40
constexpr int S2_STRIDE = 44;           // 40 + 4 pad
constexpr int F2H = TH + 8;             // 16
constexpr int NTHREADS = 576;           // 9 waves: one wave per dy
constexpr int TILES_X = W_ / TW;        // 5
constexpr int TILES_Y = H_ / TH;        // 10

__global__ __launch_bounds__(NTHREADS)
void corr_leaky_kernel(const float* __restrict__ f1,
                       const float* __restrict__ f2,
                       float* __restrict__ out) {
    __shared__ float s1[CK][TH][S1_STRIDE];
    __shared__ float s2[CK][F2H][S2_STRIDE];

    const int t  = threadIdx.x;
    const int g  = t >> 6;     // dy group, 0..8 (one wave each)
    const int lt = t & 63;
    const int r  = lt >> 3;    // local row 0..7
    const int xg = lt & 7;     // x-group: pixels 4*xg .. 4*xg+3

    const int bid  = blockIdx.x;
    const int n    = bid / (TILES_X * TILES_Y);
    const int trem = bid % (TILES_X * TILES_Y);
    const int y0   = (trem / TILES_X) * TH;
    const int x0   = (trem % TILES_X) * TW;

    const int HW = H_ * W_;
    const float* f1n = f1 + (size_t)n * C_ * HW;
    const float* f2n = f2 + (size_t)n * C_ * HW;

    float acc[9][4];
#pragma unroll
    for (int dx = 0; dx < 9; ++dx)
#pragma unroll
        for (int p = 0; p < 4; ++p) acc[dx][p] = 0.0f;

    const int rg = r + g;  // row inside haloed f2 tile (0..15)

    for (int c0 = 0; c0 < C_; c0 += CK) {
        // ---- stage f1 tile: CK*8*32 = 2048 floats, coalesced ----
        for (int i = t; i < CK * TH * TW; i += NTHREADS) {
            const int cc  = i >> 8;       // / 256
            const int rem = i & 255;
            const int ly  = rem >> 5;     // / 32
            const int lx  = rem & 31;
            s1[cc][ly][lx] = f1n[(c0 + cc) * HW + (y0 + ly) * W_ + (x0 + lx)];
        }
        // ---- stage f2 halo tile: CK*16*40 = 5120 floats, zero-padded ----
        for (int i = t; i < CK * F2H * F2W; i += NTHREADS) {
            const int cc  = i / (F2H * F2W);
            int rem       = i - cc * (F2H * F2W);
            const int ly  = rem / F2W;
            const int lx  = rem - ly * F2W;
            const int gy  = y0 + ly - MAXD;
            const int gx  = x0 + lx - MAXD;
            float v = 0.0f;
            if ((unsigned)gy < (unsigned)H_ && (unsigned)gx < (unsigned)W_)
                v = f2n[(c0 + cc) * HW + gy * W_ + gx];
            s2[cc][ly][lx] = v;
        }
        __syncthreads();

        // ---- compute: per channel, 4 b128 LDS reads -> 36 FMAs ----
#pragma unroll
        for (int cc = 0; cc < CK; ++cc) {
            const float4 a4 = *(const float4*)&s1[cc][r][4 * xg];
            const float4 b0 = *(const float4*)&s2[cc][rg][4 * xg];
            const float4 b1 = *(const float4*)&s2[cc][rg][4 * xg + 4];
            const float4 b2 = *(const float4*)&s2[cc][rg][4 * xg + 8];
            const float a[4]  = {a4.x, a4.y, a4.z, a4.w};
            const float b[12] = {b0.x, b0.y, b0.z, b0.w,
                                 b1.x, b1.y, b1.z, b1.w,
                                 b2.x, b2.y, b2.z, b2.w};
#pragma unroll
            for (int dx = 0; dx < 9; ++dx)
#pragma unroll
                for (int p = 0; p < 4; ++p)
                    acc[dx][p] = fmaf(a[p], b[p + dx], acc[dx][p]);
        }
        __syncthreads();
    }

    // ---- epilogue: scale, LeakyReLU, float4 stores ----
    const float inv_c = 1.0f / (float)C_;
    const int y  = y0 + r;
    const int xb = x0 + 4 * xg;
#pragma unroll
    for (int dx = 0; dx < 9; ++dx) {
        float4 v;
        float e0 = acc[dx][0] * inv_c;
        float e1 = acc[dx][1] * inv_c;
        float e2 = acc[dx][2] * inv_c;
        float e3 = acc[dx][3] * inv_c;
        v.x = e0 > 0.0f ? e0 : 0.1f * e0;
        v.y = e1 > 0.0f ? e1 : 0.1f * e1;
        v.z = e2 > 0.0f ? e2 : 0.1f * e2;
        v.w = e3 > 0.0f ? e3 : 0.1f * e3;
        const int ch = g * 9 + dx;
        const size_t off = ((size_t)(n * 81 + ch) * H_ + y) * W_ + xb;
        *(float4*)&out[off] = v;
    }
}

extern "C" void kernel_launch(void* const* d_in, const int* in_sizes, int n_in,
                              void* d_out, int out_size, void* d_ws, size_t ws_size,
                              hipStream_t stream) {
    const float* f1 = (const float*)d_in[0];
    const float* f2 = (const float*)d_in[1];
    float* out = (float*)d_out;
    const int nblocks = N_ * TILES_X * TILES_Y;  // 8 * 50 = 400
    corr_leaky_kernel<<<dim3(nblocks), dim3(NTHREADS), 0, stream>>>(f1, f2, out);
}